// Round 10
// baseline (1072.189 us; speedup 1.0000x reference)
//
#include <hip/hip_runtime.h>
#include <math.h>

#define N_ROWS 4096
#define E_DIM  512
#define C_CLS  50257
#define NIT    197          // ceil(50257/256) 256-col block-iterations
#define NCT    788          // partials per row: NIT * 4 waves (64 cols each)
#define NCG    8            // col groups == XCD count
#define NRT    64           // row tiles (4096/64)
#define COS_M  (-0.6536436208636119f)   // cos(4.0)
#define SIN_M  (-0.7568024953079282f)   // sin(4.0)
#define EPSN   1e-12f

typedef __bf16 bf16x8 __attribute__((ext_vector_type(8)));
typedef float  f32x4  __attribute__((ext_vector_type(4)));
typedef unsigned short ushort8 __attribute__((ext_vector_type(8)));

__device__ inline unsigned short f2bf(float f) {
  unsigned int u = __float_as_uint(f);
  u += 0x7FFFu + ((u >> 16) & 1u);     // round-to-nearest-even
  return (unsigned short)(u >> 16);
}

// w row L2-normalize, wave-private (no barriers): 4 rows/block, 1 wave/row.
__global__ __launch_bounds__(256) void k_norm_w(const float* __restrict__ src,
                                                unsigned short* __restrict__ dst) {
  int row = blockIdx.x * 4 + (threadIdx.x >> 6);
  if (row >= C_CLS) return;
  int lane = threadIdx.x & 63;
  const float4* p = (const float4*)(src + (size_t)row * E_DIM);
  float4 v0 = p[lane * 2], v1 = p[lane * 2 + 1];
  float ss = v0.x*v0.x + v0.y*v0.y + v0.z*v0.z + v0.w*v0.w
           + v1.x*v1.x + v1.y*v1.y + v1.z*v1.z + v1.w*v1.w;
  #pragma unroll
  for (int m = 32; m > 0; m >>= 1) ss += __shfl_xor(ss, m, 64);
  float inv = 1.0f / fmaxf(sqrtf(ss), EPSN);
  ushort8 o;
  o[0]=f2bf(v0.x*inv); o[1]=f2bf(v0.y*inv); o[2]=f2bf(v0.z*inv); o[3]=f2bf(v0.w*inv);
  o[4]=f2bf(v1.x*inv); o[5]=f2bf(v1.y*inv); o[6]=f2bf(v1.z*inv); o[7]=f2bf(v1.w*inv);
  *(ushort8*)(dst + (size_t)row * E_DIM + lane * 8) = o;
}

// A-resident GEMM (cos = nx.nw^T) + fused exp-sum, x normalized IN-KERNEL.
// Block = 256 thr (4 waves). A-tile 64 rows x 512 K bf16 = 64 KB LDS,
// built in the prologue (read x f32, row-normalize, ds_write in MFMA
// fragment order), ONE __syncthreads, then a barrier-free main loop.
// Each wave owns a 64x64 slab per 256-col iteration: B streams
// global->register (3-slot rotation, depth-2 prefetch, NO LDS), A frags
// ds_read from the static tile (read-only => no hazards, no lgkm drains).
// Grid (NCG=8 fastest, NRT=64): XCD = linear%8 = cgroup, so each XCD's 64
// resident blocks (all rtiles of ONE cgroup) share one streaming B range in
// its L2; L3 backs the 8 streams (B = 51.5 MB << 256 MB).
// 512 blocks = exactly 2/CU (LDS-capped); acc[4][4]=64 VGPR -> no spills.
// No max-prescan: cos in [-1,1] so exp() is safe; partials are plain sums.
__global__ __launch_bounds__(256, 2) void k_gemm(const float* __restrict__ x,
                                                 const unsigned short* __restrict__ nw,
                                                 const int* __restrict__ label,
                                                 float* __restrict__ pl,
                                                 float* __restrict__ tbf) {
  __shared__ bf16x8 ldsA[64 * 64];   // 64 chunks x 1 KB = 64 KB

  int cgrp = blockIdx.x;               // 0..7 fastest -> XCD = cgrp
  int rtile = blockIdx.y;              // 0..63
  int tid = threadIdx.x;
  int wave = tid >> 6;                 // 0..3
  int lane = tid & 63;
  int q = lane >> 4;
  int l15 = lane & 15;
  int rowTile = rtile * 64;

  // ---- Prologue: normalize 16 rows per wave of x into LDS fragment order.
  // Fragment layout: chunk c = kt*4 + g16 holds, at slot q*16+l15, the bf16
  // elems A[g16*16+l15][kt*32+q*8 .. +7]. Source lane s of row wr supplies
  // elems [s*8, s*8+8): kt = s>>2, q = s&3, g16 = wr>>4, l15 = wr&15.
  #pragma unroll
  for (int r = 0; r < 16; r++) {
    int wr = wave * 16 + r;            // local row 0..63
    const float4* px = (const float4*)(x + (size_t)(rowTile + wr) * E_DIM);
    float4 v0 = px[lane * 2], v1 = px[lane * 2 + 1];
    float ss = v0.x*v0.x + v0.y*v0.y + v0.z*v0.z + v0.w*v0.w
             + v1.x*v1.x + v1.y*v1.y + v1.z*v1.z + v1.w*v1.w;
    #pragma unroll
    for (int m = 32; m > 0; m >>= 1) ss += __shfl_xor(ss, m, 64);
    float inv = 1.0f / fmaxf(sqrtf(ss), EPSN);
    ushort8 o;
    o[0]=f2bf(v0.x*inv); o[1]=f2bf(v0.y*inv); o[2]=f2bf(v0.z*inv); o[3]=f2bf(v0.w*inv);
    o[4]=f2bf(v1.x*inv); o[5]=f2bf(v1.y*inv); o[6]=f2bf(v1.z*inv); o[7]=f2bf(v1.w*inv);
    int kt = lane >> 2, qs = lane & 3;
    ldsA[(kt * 4 + (wr >> 4)) * 64 + qs * 16 + (wr & 15)] = *(bf16x8*)&o;
  }
  __syncthreads();   // the ONLY barrier

  // Preload this wave's 16 output-row labels (fixed across all iterations).
  int labR[4][4];
  #pragma unroll
  for (int i = 0; i < 4; i++)
    #pragma unroll
    for (int reg = 0; reg < 4; reg++)
      labR[i][reg] = label[rowTile + i * 16 + 4 * q + reg];

  // ---- Main loop over this cgroup's 256-col iterations.
  int itBeg = (cgrp * NIT) / NCG;
  int itEnd = ((cgrp + 1) * NIT) / NCG;
  for (int it = itBeg; it < itEnd; it++) {
    int colBase = it * 256 + wave * 64;
    const unsigned short* gB[4];
    #pragma unroll
    for (int j = 0; j < 4; j++) {
      int cls = colBase + j * 16 + l15;
      if (cls >= C_CLS) cls = C_CLS - 1;      // clamp; masked in epilogue
      gB[j] = nw + (size_t)cls * E_DIM + q * 8;
    }

    // B rotation: slot kt%3 holds stage kt.
    bf16x8 bfr[3][4];
    #pragma unroll
    for (int j = 0; j < 4; j++) {
      bfr[0][j] = *(const bf16x8*)(gB[j]);
      bfr[1][j] = *(const bf16x8*)(gB[j] + 32);
    }

    f32x4 acc[4][4] = {};

    #pragma unroll
    for (int kt = 0; kt < 16; kt++) {
      int s = kt % 3;
      if (kt + 2 < 16) {
        int s2 = (kt + 2) % 3;
        #pragma unroll
        for (int j = 0; j < 4; j++)
          bfr[s2][j] = *(const bf16x8*)(gB[j] + (kt + 2) * 32);
      }
      bf16x8 afr[4];
      #pragma unroll
      for (int i = 0; i < 4; i++)
        afr[i] = ldsA[(kt * 4 + i) * 64 + lane];
      #pragma unroll
      for (int j = 0; j < 4; j++)
        #pragma unroll
        for (int i = 0; i < 4; i++)
          acc[i][j] = __builtin_amdgcn_mfma_f32_16x16x32_bf16(afr[i], bfr[s][j],
                                                              acc[i][j], 0, 0, 0);
    }

    // Epilogue. C/D: row = 4*q + reg (within 16), col = l15.
    #pragma unroll
    for (int i = 0; i < 4; i++) {
      #pragma unroll
      for (int reg = 0; reg < 4; reg++) {
        int grow = rowTile + i * 16 + 4 * q + reg;
        int lab = labR[i][reg];
        float e = 0.f;
        #pragma unroll
        for (int j = 0; j < 4; j++) {
          int col = colBase + j * 16 + l15;
          float v = acc[i][j][reg];
          if (col < C_CLS) {
            e += __expf(v);
            if (col == lab) tbf[grow] = v;   // bf16-GEMM cos at label position
          }
        }
        #pragma unroll
        for (int m = 1; m < 16; m <<= 1) e += __shfl_xor(e, m, 64);
        if (l15 == 0) pl[(size_t)grow * NCT + it * 4 + wave] = e;
      }
    }
  }
}

// Per row: sum exp-partials, compute precise fp32 target cosine, swap in
// margin logit, mean-reduce. 1 block/row, 256 thr.
__global__ __launch_bounds__(256) void k_reduce(const float* __restrict__ pl,
                                                const float* __restrict__ x,
                                                const float* __restrict__ w,
                                                const int* __restrict__ label,
                                                const float* __restrict__ tbf,
                                                float* __restrict__ out) {
  int row = blockIdx.x;
  int tid = threadIdx.x;
  int lab = label[row];
  float s = 0.f;
  for (int j = tid; j < NCT; j += 256) s += pl[(size_t)row * NCT + j];
  const float2* px = (const float2*)(x + (size_t)row * E_DIM);
  const float2* pw = (const float2*)(w + (size_t)lab * E_DIM);
  float2 a = px[tid], b = pw[tid];
  float sx = a.x*a.x + a.y*a.y;
  float sw = b.x*b.x + b.y*b.y;
  float sd = a.x*b.x + a.y*b.y;
  #pragma unroll
  for (int off = 32; off > 0; off >>= 1) {
    s  += __shfl_down(s, off, 64);
    sx += __shfl_down(sx, off, 64);
    sw += __shfl_down(sw, off, 64);
    sd += __shfl_down(sd, off, 64);
  }
  __shared__ float sb[4][4];
  if ((tid & 63) == 0) {
    int wv = tid >> 6;
    sb[0][wv] = s; sb[1][wv] = sx; sb[2][wv] = sw; sb[3][wv] = sd;
  }
  __syncthreads();
  if (tid == 0) {
    float S  = sb[0][0] + sb[0][1] + sb[0][2] + sb[0][3];
    float SX = sb[1][0] + sb[1][1] + sb[1][2] + sb[1][3];
    float SW = sb[2][0] + sb[2][1] + sb[2][2] + sb[2][3];
    float SD = sb[3][0] + sb[3][1] + sb[3][2] + sb[3][3];
    float t = SD / (fmaxf(sqrtf(SX), EPSN) * fmaxf(sqrtf(SW), EPSN));
    float tb = tbf[row];
    float sint = sqrtf(fmaxf(0.f, 1.f - t * t));
    float cosm = t * COS_M - sint * SIN_M;
    float Sp = S - __expf(tb) + __expf(cosm);   // replace target logit
    float loss = logf(Sp) - cosm;
    atomicAdd(out, loss * (1.0f / N_ROWS));
  }
}

extern "C" void kernel_launch(void* const* d_in, const int* in_sizes, int n_in,
                              void* d_out, int out_size, void* d_ws, size_t ws_size,
                              hipStream_t stream) {
  const float* x = (const float*)d_in[0];
  const int* label = (const int*)d_in[1];
  const float* w = (const float*)d_in[2];
  float* out = (float*)d_out;
  char* ws = (char*)d_ws;

  size_t off = 0;
  unsigned short* nw = (unsigned short*)(ws + off); off += (size_t)C_CLS * E_DIM * 2;   // 51.5 MB
  float* tbf = (float*)(ws + off); off += (size_t)N_ROWS * 4;
  float* pl  = (float*)(ws + off); off += (size_t)N_ROWS * NCT * 4;                     // 12.9 MB

  hipMemsetAsync(d_out, 0, sizeof(float), stream);
  k_norm_w<<<(C_CLS + 3) / 4, 256, 0, stream>>>(w, nw);
  dim3 g(NCG, NRT);
  k_gemm<<<g, 256, 0, stream>>>(x, nw, label, pl, tbf);
  k_reduce<<<N_ROWS, 256, 0, stream>>>(pl, x, w, label, tbf, out);
}

// Round 11
// 761.992 us; speedup vs baseline: 1.4071x; 1.4071x over previous
//
#include <hip/hip_runtime.h>
#include <math.h>

#define N_ROWS 4096
#define E_DIM  512
#define C_CLS  50257
#define NCT2   786          // partials per row: 393 col-tiles * 2 wave-halves
#define NTILE  393          // ceil(50257/128)
#define COS_M  (-0.6536436208636119f)   // cos(4.0)
#define SIN_M  (-0.7568024953079282f)   // sin(4.0)
#define EPSN   1e-12f

#define WAITCNT_LGKM0 0xC07F   // lgkmcnt(0), vmcnt/exp ignored

typedef __bf16 bf16x8 __attribute__((ext_vector_type(8)));
typedef float  f32x4  __attribute__((ext_vector_type(4)));
typedef unsigned short ushort8 __attribute__((ext_vector_type(8)));

__device__ inline unsigned short f2bf(float f) {
  unsigned int u = __float_as_uint(f);
  u += 0x7FFFu + ((u >> 16) & 1u);     // round-to-nearest-even
  return (unsigned short)(u >> 16);
}

// Row L2-normalize f32 -> bf16, wave-private (no barriers): 4 rows/block.
__global__ __launch_bounds__(256) void k_norm(const float* __restrict__ src,
                                              unsigned short* __restrict__ dst,
                                              int nrows) {
  int row = blockIdx.x * 4 + (threadIdx.x >> 6);
  if (row >= nrows) return;
  int lane = threadIdx.x & 63;
  const float4* p = (const float4*)(src + (size_t)row * E_DIM);
  float4 v0 = p[lane * 2], v1 = p[lane * 2 + 1];
  float ss = v0.x*v0.x + v0.y*v0.y + v0.z*v0.z + v0.w*v0.w
           + v1.x*v1.x + v1.y*v1.y + v1.z*v1.z + v1.w*v1.w;
  #pragma unroll
  for (int m = 32; m > 0; m >>= 1) ss += __shfl_xor(ss, m, 64);
  float inv = 1.0f / fmaxf(sqrtf(ss), EPSN);
  ushort8 o;
  o[0]=f2bf(v0.x*inv); o[1]=f2bf(v0.y*inv); o[2]=f2bf(v0.z*inv); o[3]=f2bf(v0.w*inv);
  o[4]=f2bf(v1.x*inv); o[5]=f2bf(v1.y*inv); o[6]=f2bf(v1.z*inv); o[7]=f2bf(v1.w*inv);
  *(ushort8*)(dst + (size_t)row * E_DIM + lane * 8) = o;
}

// 128x128-tile GEMM (cos = nx.nw^T) + fused exp-sum.
// B-ONLY through LDS (register-staged double buffer, depth-2, lgkm-only
// barrier — no global_load_lds so vmcnt never ties to the barrier).
// A fragments: DIRECT global->register, depth-1 prefetch; each A frag is
// private to a row-half wave pair and A (4 MB) is L2/L3-resident, so the
// loads are cheap and their vmcnt waits cross barriers freely.
// Per stage per block: 16 ds_read + 8 ds_write (~288 cyc) vs 64 MFMA
// (~310 cyc) — LDS pipe no longer binding (was 48 ops in R8).
// 4 waves (2x2 quadrants of 64x64). BK=32, 16 stages.
// Hazards: ldsB[p^1] writes at stage k safe — all waves' p^1 reads retired
// at their lgkmcnt(0) before barrier k-1. Grid: rtile fastest (B L2 reuse,
// FETCH=203 MB measured in R8).
// No max-prescan: cos in [-1,1] so exp() is safe; partials are plain sums.
__global__ __launch_bounds__(256, 4) void k_gemm(const unsigned short* __restrict__ nx,
                                                 const unsigned short* __restrict__ nw,
                                                 const int* __restrict__ label,
                                                 float* __restrict__ pl,
                                                 float* __restrict__ tbf) {
  __shared__ bf16x8 ldsB[2][8 * 64];   // 2 x 8 KB

  int rtile = blockIdx.x;              // 0..31 fastest -> B reuse in L2/L3
  int ctile = blockIdx.y;              // 0..392
  int tid = threadIdx.x;
  int wave = tid >> 6;
  int lane = tid & 63;
  int q = lane >> 4;
  int l15 = lane & 15;
  int wr = wave >> 1;
  int wc = wave & 1;
  int rowTile = rtile * 128;
  int colTile = ctile * 128;

  // B staging: wave stages chunks {2w, 2w+1}; chunk c covers cols
  // colTile + c*16 + l15, elems kt*32 + q*8 .. +7 (16 B/lane).
  const unsigned short* gB[2];
  #pragma unroll
  for (int t = 0; t < 2; t++) {
    int cls = colTile + (wave * 2 + t) * 16 + l15;
    if (cls >= C_CLS) cls = C_CLS - 1;          // clamp; masked in epilogue
    gB[t] = nw + (size_t)cls * E_DIM + q * 8;
  }
  // A fragments: wave (wr) reads rows rowTile + wr*64 + i*16 + l15.
  const unsigned short* gA =
      nx + (size_t)(rowTile + wr * 64 + l15) * E_DIM + q * 8;

  // Prologue: B stages 0,1 -> regs; A stage 0 -> regs; write B stage 0.
  bf16x8 rB[2][2];
  #pragma unroll
  for (int t = 0; t < 2; t++) {
    rB[0][t] = *(const bf16x8*)(gB[t]);
    rB[1][t] = *(const bf16x8*)(gB[t] + 32);
  }
  bf16x8 afr[2][4];
  #pragma unroll
  for (int i = 0; i < 4; i++)
    afr[0][i] = *(const bf16x8*)(gA + (size_t)i * 16 * E_DIM);
  #pragma unroll
  for (int t = 0; t < 2; t++)
    ldsB[0][(wave * 2 + t) * 64 + lane] = rB[0][t];
  __builtin_amdgcn_s_waitcnt(WAITCNT_LGKM0);
  __builtin_amdgcn_s_barrier();

  f32x4 acc[4][4] = {};

  #pragma unroll
  for (int kt = 0; kt < 16; kt++) {
    int p = kt & 1;
    // B fragments for stage kt (this wave's 64 cols).
    bf16x8 bfr[4];
    #pragma unroll
    for (int j = 0; j < 4; j++)
      bfr[j] = ldsB[p][(wc * 4 + j) * 64 + lane];
    // Stage kt+1 B: regs -> buf p^1 (precise vmcnt waits; issued 2 stages ago).
    if (kt + 1 < 16) {
      #pragma unroll
      for (int t = 0; t < 2; t++)
        ldsB[p ^ 1][(wave * 2 + t) * 64 + lane] = rB[(kt + 1) & 1][t];
    }
    // Stage kt+2 B: global -> regs.
    if (kt + 2 < 16) {
      #pragma unroll
      for (int t = 0; t < 2; t++)
        rB[p][t] = *(const bf16x8*)(gB[t] + (kt + 2) * 32);
    }
    // Stage kt+1 A: global -> regs (L2-hot; consumed next stage).
    if (kt + 1 < 16) {
      #pragma unroll
      for (int i = 0; i < 4; i++)
        afr[p ^ 1][i] =
            *(const bf16x8*)(gA + (size_t)i * 16 * E_DIM + (kt + 1) * 32);
    }
    #pragma unroll
    for (int i = 0; i < 4; i++)
      #pragma unroll
      for (int j = 0; j < 4; j++)
        acc[i][j] = __builtin_amdgcn_mfma_f32_16x16x32_bf16(afr[p][i], bfr[j],
                                                            acc[i][j], 0, 0, 0);
    __builtin_amdgcn_s_waitcnt(WAITCNT_LGKM0);   // LDS ops retired; vmcnt untouched
    __builtin_amdgcn_s_barrier();
  }

  // Epilogue: C/D layout row = 4*q + reg (within 16), col = l15.
  // Wave covers rows [rowTile + wr*64, +64), cols [colTile + wc*64, +64).
  int colW = colTile + wc * 64;
  #pragma unroll
  for (int msub = 0; msub < 4; msub++) {
    #pragma unroll
    for (int reg = 0; reg < 4; reg++) {
      int grow = rowTile + wr * 64 + msub * 16 + 4 * q + reg;
      int lab = label[grow];
      float e = 0.f;
      #pragma unroll
      for (int ns = 0; ns < 4; ns++) {
        int col = colW + ns * 16 + l15;
        float v = acc[msub][ns][reg];
        if (col < C_CLS) {
          e += __expf(v);
          if (col == lab) tbf[grow] = v;   // bf16-GEMM cos at label position
        }
      }
      #pragma unroll
      for (int m = 1; m < 16; m <<= 1) e += __shfl_xor(e, m, 64);
      if (l15 == 0) pl[(size_t)grow * NCT2 + (size_t)ctile * 2 + wc] = e;
    }
  }
}

// Per row: sum exp-partials, precise fp32 target cosine (fused), swap in
// margin logit, mean-reduce. 1 block/row, 256 thr.
__global__ __launch_bounds__(256) void k_reduce(const float* __restrict__ pl,
                                                const float* __restrict__ x,
                                                const float* __restrict__ w,
                                                const int* __restrict__ label,
                                                const float* __restrict__ tbf,
                                                float* __restrict__ out) {
  int row = blockIdx.x;
  int tid = threadIdx.x;
  int lab = label[row];
  float s = 0.f;
  for (int j = tid; j < NCT2; j += 256) s += pl[(size_t)row * NCT2 + j];
  const float2* px = (const float2*)(x + (size_t)row * E_DIM);
  const float2* pw = (const float2*)(w + (size_t)lab * E_DIM);
  float2 a = px[tid], b = pw[tid];
  float sx = a.x*a.x + a.y*a.y;
  float sw = b.x*b.x + b.y*b.y;
  float sd = a.x*b.x + a.y*b.y;
  #pragma unroll
  for (int off = 32; off > 0; off >>= 1) {
    s  += __shfl_down(s, off, 64);
    sx += __shfl_down(sx, off, 64);
    sw += __shfl_down(sw, off, 64);
    sd += __shfl_down(sd, off, 64);
  }
  __shared__ float sb[4][4];
  if ((tid & 63) == 0) {
    int wv = tid >> 6;
    sb[0][wv] = s; sb[1][wv] = sx; sb[2][wv] = sw; sb[3][wv] = sd;
  }
  __syncthreads();
  if (tid == 0) {
    float S  = sb[0][0] + sb[0][1] + sb[0][2] + sb[0][3];
    float SX = sb[1][0] + sb[1][1] + sb[1][2] + sb[1][3];
    float SW = sb[2][0] + sb[2][1] + sb[2][2] + sb[2][3];
    float SD = sb[3][0] + sb[3][1] + sb[3][2] + sb[3][3];
    float t = SD / (fmaxf(sqrtf(SX), EPSN) * fmaxf(sqrtf(SW), EPSN));
    float tb = tbf[row];
    float sint = sqrtf(fmaxf(0.f, 1.f - t * t));
    float cosm = t * COS_M - sint * SIN_M;
    float Sp = S - __expf(tb) + __expf(cosm);   // replace target logit
    float loss = logf(Sp) - cosm;
    atomicAdd(out, loss * (1.0f / N_ROWS));
  }
}

extern "C" void kernel_launch(void* const* d_in, const int* in_sizes, int n_in,
                              void* d_out, int out_size, void* d_ws, size_t ws_size,
                              hipStream_t stream) {
  const float* x = (const float*)d_in[0];
  const int* label = (const int*)d_in[1];
  const float* w = (const float*)d_in[2];
  float* out = (float*)d_out;
  char* ws = (char*)d_ws;

  size_t off = 0;
  unsigned short* nx = (unsigned short*)(ws + off); off += (size_t)N_ROWS * E_DIM * 2;  // 4 MB
  unsigned short* nw = (unsigned short*)(ws + off); off += (size_t)C_CLS * E_DIM * 2;   // 51.5 MB
  float* tbf = (float*)(ws + off); off += (size_t)N_ROWS * 4;
  float* pl  = (float*)(ws + off); off += (size_t)N_ROWS * NCT2 * 4;                    // 12.9 MB

  hipMemsetAsync(d_out, 0, sizeof(float), stream);
  k_norm<<<(C_CLS + 3) / 4, 256, 0, stream>>>(w, nw, C_CLS);
  k_norm<<<N_ROWS / 4, 256, 0, stream>>>(x, nx, N_ROWS);
  dim3 g(N_ROWS / 128, NTILE);
  k_gemm<<<g, 256, 0, stream>>>(nx, nw, label, pl, tbf);
  k_reduce<<<N_ROWS, 256, 0, stream>>>(pl, x, w, label, tbf, out);
}